// Round 3
// baseline (2654.238 us; speedup 1.0000x reference)
//
#include <hip/hip_runtime.h>
#include <cstdint>
#include <cstddef>

#define TSTEPS 256
#define NB     256
#define NH     1024
#define NIN    105
#define NOUT   33

using half8 = __attribute__((ext_vector_type(8))) _Float16;
using f32x4 = __attribute__((ext_vector_type(4))) float;

// ws layout (halves):
//   Wrecf [0,1048576)        [64 nt][32 kk][64 lane][8]
//   Wcf   +131072            [64 nt][ 4 kk][64 lane][8]
//   Wof   +49152             [ 3 nt][32 kk][64 lane][8]
//   arr   (int*) 128 flags; xcdArr (int*) 128
//
// h history / exchange: fp16, packed into the noise buffer (float* d_in[1]):
//   h(t, group g, local row rl, col c) at half index
//       t*524288 + g*65536 + rl*1024 + c
//   Safety: noise slab t+1 bytes for group g are read only by wave4 of the
//   group's blocks during their step t, and those loads are drained (consumed)
//   before B1(t) < B2(t) < flag(t+2). Writers of hist slab t+1 poll all 16
//   group flags >= t+2 first. Row/col partition within the group is exact.
//
// k_rnn wave roles (384 threads = 6 waves):
//   waves 0-3: K-quarter w (256 wide), BOTH m halves; B-frags in registers.
//              Own nt=w for the update (8 softplus/lane).
//   wave 4   : input pipeline. Pre-B0: issue x/noise loads for t+1.
//              Post-B0: cvt + 32 MFMA -> pAl[(t+1)&1] (double-buffered LDS).
//   wave 5   : poll-only wave (no outstanding vmem -> clean volatile loads).

// ---------------------------------------------------------------------------
__global__ __launch_bounds__(256) void k_convert(
    const float* __restrict__ W_sens, const float* __restrict__ W_rule,
    const float* __restrict__ W_rec,  const float* __restrict__ W_out,
    _Float16* __restrict__ Wrecf, _Float16* __restrict__ Wcf,
    _Float16* __restrict__ Wof)
{
    int tid  = blockIdx.x * 256 + threadIdx.x;
    int lane = tid & 63;
    int orow = lane & 15;
    int col0 = (lane >> 4) * 8;
    if (tid < 64 * 32 * 64) {
        int kk = (tid >> 6) & 31, n = tid >> 11;
        int o = n * 16 + orow, k0 = kk * 32 + col0;
        const float* s = W_rec + (size_t)o * NH + k0;
        _Float16* d = Wrecf + (size_t)tid * 8;
        #pragma unroll
        for (int j = 0; j < 8; ++j) d[j] = (_Float16)s[j];
    } else if (tid < 64 * 32 * 64 + 64 * 4 * 64) {
        int t2 = tid - 64 * 32 * 64;
        int kk = (t2 >> 6) & 3, n = t2 >> 8;
        int o = n * 16 + orow, k0 = kk * 32 + col0;
        _Float16* d = Wcf + (size_t)t2 * 8;
        #pragma unroll
        for (int j = 0; j < 8; ++j) {
            int k = k0 + j;
            float v = 0.f;
            if (k < 85)       v = W_sens[o * 85 + k];
            else if (k < NIN) v = W_rule[o * 20 + (k - 85)];
            d[j] = (_Float16)v;
        }
    } else {
        int t3 = tid - (64 * 32 * 64 + 64 * 4 * 64);
        int kk = (t3 >> 6) & 31, n = t3 >> 11;
        int o = n * 16 + orow, k0 = kk * 32 + col0;
        _Float16* d = Wof + (size_t)t3 * 8;
        #pragma unroll
        for (int j = 0; j < 8; ++j)
            d[j] = (o < NOUT) ? (_Float16)W_out[(size_t)o * NH + k0 + j]
                              : (_Float16)0.f;
    }
}

__global__ __launch_bounds__(256) void k_init(int* __restrict__ flags)
{
    if (threadIdx.x < 256) flags[threadIdx.x] = 0;  // arr[128] + xcdArr[128]
}

// ---------------------------------------------------------------------------
__global__ __launch_bounds__(384, 2) void k_rnn(
    const float* __restrict__ x, float* __restrict__ noise,
    const float* __restrict__ b_sens, const float* __restrict__ b_rec,
    const _Float16* __restrict__ Wrecf, const _Float16* __restrict__ Wcf,
    int* __restrict__ arr, int* __restrict__ xcdArr)
{
    __shared__ float red[4][2][3][64][4];   // 24 KB [nt][m][slot][lane][r]
    __shared__ float pAl[2][2][4][64][4];   // 16 KB [buf][m][nt][lane][r]
    __shared__ int sFast;

    const int tid  = threadIdx.x;
    const int blk  = blockIdx.x;
    const int g    = blk & 7, s = blk >> 3;
    const int wave = tid >> 6, lane = tid & 63;
    const int mrow = lane & 15, q = lane >> 4;
    const half8* Wr8 = (const half8*)Wrecf;
    const half8* Wc8 = (const half8*)Wcf;
    _Float16* hist = (_Float16*)noise;
    volatile int* varr = (volatile int*)arr;

    // ---- XCD uniformity check (runtime-select fast/safe path) ----
    int xcd;
    asm volatile("s_getreg_b32 %0, hwreg(20, 0, 4)" : "=s"(xcd)); // HW_REG_XCC_ID
    if (tid == 0)
        __hip_atomic_store(&xcdArr[blk], xcd + 1, __ATOMIC_RELEASE,
                           __HIP_MEMORY_SCOPE_AGENT);
    if (wave == 0) {
        int idx = g + (lane & 15) * 8;   // my group's 16 block ids: g + 8*s
        int v = 0;
        for (int it = 0; it < (1 << 22); ++it) {
            v = __hip_atomic_load(&xcdArr[idx], __ATOMIC_ACQUIRE,
                                  __HIP_MEMORY_SCOPE_AGENT);
            if (__all(v >= 1)) break;
            __builtin_amdgcn_s_sleep(8);
        }
        if (lane == 0) sFast = __all(v == xcd + 1) ? 1 : 0;
    }

    // ---- per-role persistent state ----
    half8 bf[4][8];    // compute waves: B frags (128 VGPR), live whole kernel
    float hm[2][4];    // compute waves: running h (m, r) for owned nt = wave
    half8 wcb[4][4];   // wave4: W_in B frags
    float bias4[4];    // wave4

    if (wave < 4) {
        #pragma unroll
        for (int nt = 0; nt < 4; ++nt)
            #pragma unroll
            for (int kkl = 0; kkl < 8; ++kkl)
                bf[nt][kkl] =
                    Wr8[(size_t)((4 * s + nt) * 32 + wave * 8 + kkl) * 64 + lane];
        #pragma unroll
        for (int m = 0; m < 2; ++m)
            #pragma unroll
            for (int r = 0; r < 4; ++r) hm[m][r] = 0.f;
    } else if (wave == 4) {
        #pragma unroll
        for (int nt = 0; nt < 4; ++nt) {
            int o = s * 64 + nt * 16 + mrow;
            bias4[nt] = b_sens[o] + b_rec[o];
            #pragma unroll
            for (int kk = 0; kk < 4; ++kk)
                wcb[nt][kk] = Wc8[((4 * s + nt) * 4 + kk) * 64 + lane];
        }
        // in_gemm(0) -> pAl[0]
        #pragma unroll
        for (int m = 0; m < 2; ++m) {
            const float* xrow = x + (size_t)(g * 32 + m * 16 + mrow) * NIN;
            half8 af[4];
            #pragma unroll
            for (int kk = 0; kk < 4; ++kk)
                #pragma unroll
                for (int j = 0; j < 8; ++j) {
                    int c = kk * 32 + q * 8 + j;
                    af[kk][j] = (_Float16)((c < NIN) ? xrow[c] : 0.f);
                }
            #pragma unroll
            for (int nt = 0; nt < 4; ++nt) {
                f32x4 c;
                #pragma unroll
                for (int r = 0; r < 4; ++r)
                    c[r] = noise[(size_t)(g * 32 + m * 16 + q * 4 + r) * NH
                                 + s * 64 + nt * 16 + mrow] + bias4[nt];
                #pragma unroll
                for (int kk = 0; kk < 4; ++kk)
                    c = __builtin_amdgcn_mfma_f32_16x16x32_f16(af[kk],
                                                        wcb[nt][kk], c, 0, 0, 0);
                *(f32x4*)&pAl[0][m][nt][lane][0] = c;
            }
        }
    }
    __syncthreads();               // drains wave4 noise(0) loads + pAl writes
    const bool fast = (sFast != 0);
    if (tid == 0) {                // prologue-done flag = 1
        if (fast) varr[g * 16 + s] = 1;
        else __hip_atomic_store(&arr[g * 16 + s], 1, __ATOMIC_RELAXED,
                                __HIP_MEMORY_SCOPE_AGENT);
    }

    for (int t = 0; t < TSTEPS; ++t) {
        // ---- wave4: early-issue x/noise loads for t+1 (pre-B0) ----
        float xf[2][4][8];
        float nzv[2][4][4];
        if (wave == 4 && t + 1 < TSTEPS) {
            #pragma unroll
            for (int m = 0; m < 2; ++m) {
                const float* xrow = x + ((size_t)(t + 1) * NB + g * 32 + m * 16
                                         + mrow) * NIN;
                #pragma unroll
                for (int kk = 0; kk < 4; ++kk)
                    #pragma unroll
                    for (int j = 0; j < 8; ++j) {
                        int c = kk * 32 + q * 8 + j;
                        xf[m][kk][j] = (c < NIN) ? xrow[c] : 0.f;
                    }
                #pragma unroll
                for (int nt = 0; nt < 4; ++nt)
                    #pragma unroll
                    for (int r = 0; r < 4; ++r)
                        nzv[m][nt][r] =
                            noise[((size_t)(t + 1) * NB + g * 32 + m * 16
                                   + q * 4 + r) * NH + s * 64 + nt * 16 + mrow];
            }
        }
        // ---- wave5: poll all 16 group slices at >= t+1 ----
        if (wave == 5) {
            int idx = g * 16 + (lane & 15);
            if (fast) {
                for (int it = 0; it < (1 << 22); ++it) {
                    asm volatile("buffer_inv sc0" ::: "memory");  // L1 inv
                    int v = varr[idx];                            // L2 read
                    if (__all(v >= t + 1)) break;
                    __builtin_amdgcn_s_sleep(1);
                }
            } else {
                for (int it = 0; it < (1 << 22); ++it) {
                    int v = __hip_atomic_load(&arr[idx], __ATOMIC_RELAXED,
                                              __HIP_MEMORY_SCOPE_AGENT);
                    if (__all(v >= t + 1)) break;
                    __builtin_amdgcn_s_sleep(1);
                }
            }
        }
        asm volatile("s_barrier" ::: "memory");              // B0
        if (!fast) __builtin_amdgcn_fence(__ATOMIC_ACQUIRE, "agent");
        // fast: hist slab t-1 addresses are first-touch for this CU's L1
        // (t monotonic), or self-written -> no stale-L1 hazard; only the
        // flag line is re-read and wave5 invalidates it per poll iter.

        // ---- compute waves: K-loop, A = fp16 h slab t-1 (L2), B = regs ----
        f32x4 acc[2][4];
        #pragma unroll
        for (int m = 0; m < 2; ++m)
            #pragma unroll
            for (int nt = 0; nt < 4; ++nt) acc[m][nt] = (f32x4){0.f,0.f,0.f,0.f};
        if (wave < 4 && t > 0) {
            const _Float16* hR = hist + (size_t)(t - 1) * 524288
                                      + (size_t)g * 65536 + wave * 256 + q * 8;
            #pragma unroll
            for (int kkl = 0; kkl < 8; ++kkl) {
                half8 a0 = *(const half8*)(hR + (size_t)mrow * 1024 + kkl * 32);
                half8 a1 = *(const half8*)(hR + (size_t)(16 + mrow) * 1024
                                              + kkl * 32);
                #pragma unroll
                for (int nt = 0; nt < 4; ++nt) {
                    acc[0][nt] = __builtin_amdgcn_mfma_f32_16x16x32_f16(
                                     a0, bf[nt][kkl], acc[0][nt], 0, 0, 0);
                    acc[1][nt] = __builtin_amdgcn_mfma_f32_16x16x32_f16(
                                     a1, bf[nt][kkl], acc[1][nt], 0, 0, 0);
                }
            }
        }
        // ---- wave4: pA(t+1) = x·Win + noise + bias -> pAl[(t+1)&1] ----
        if (wave == 4 && t + 1 < TSTEPS) {
            const int buf = (t + 1) & 1;
            #pragma unroll
            for (int m = 0; m < 2; ++m) {
                half8 af[4];
                #pragma unroll
                for (int kk = 0; kk < 4; ++kk)
                    #pragma unroll
                    for (int j = 0; j < 8; ++j)
                        af[kk][j] = (_Float16)xf[m][kk][j];
                #pragma unroll
                for (int nt = 0; nt < 4; ++nt) {
                    f32x4 c = { nzv[m][nt][0] + bias4[nt],
                                nzv[m][nt][1] + bias4[nt],
                                nzv[m][nt][2] + bias4[nt],
                                nzv[m][nt][3] + bias4[nt] };
                    #pragma unroll
                    for (int kk = 0; kk < 4; ++kk)
                        c = __builtin_amdgcn_mfma_f32_16x16x32_f16(
                                af[kk], wcb[nt][kk], c, 0, 0, 0);
                    *(f32x4*)&pAl[buf][m][nt][lane][0] = c;
                }
            }
        }
        // ---- publish non-owned nt partials (one barrier) ----
        if (wave < 4) {
            #pragma unroll
            for (int m = 0; m < 2; ++m)
                #pragma unroll
                for (int nt = 0; nt < 4; ++nt)
                    if (nt != wave) {
                        int slot = (wave < nt) ? wave : wave - 1;
                        *(f32x4*)&red[nt][m][slot][lane][0] = acc[m][nt];
                    }
        }
        asm volatile("s_waitcnt lgkmcnt(0)\n\ts_barrier" ::: "memory");  // B1

        // ---- update owned nt = wave (8 softplus/lane) + fp16 hist store ----
        if (wave < 4) {
            // select own acc with static register indices (rule #20)
            f32x4 own[2];
            #pragma unroll
            for (int m = 0; m < 2; ++m) {
                own[m] = acc[m][0];
                #pragma unroll
                for (int nt = 1; nt < 4; ++nt)
                    if (wave == nt) own[m] = acc[m][nt];
            }
            const size_t hb = (size_t)t * 524288 + (size_t)g * 65536;
            #pragma unroll
            for (int m = 0; m < 2; ++m) {
                f32x4 r0 = *(const f32x4*)&red[wave][m][0][lane][0];
                f32x4 r1 = *(const f32x4*)&red[wave][m][1][lane][0];
                f32x4 r2 = *(const f32x4*)&red[wave][m][2][lane][0];
                f32x4 pa = *(const f32x4*)&pAl[t & 1][m][wave][lane][0];
                #pragma unroll
                for (int r = 0; r < 4; ++r) {
                    float v  = own[m][r] + r0[r] + r1[r] + r2[r] + pa[r];
                    float sp = fmaxf(v, 0.f) + __logf(1.f + __expf(-fabsf(v)));
                    float hn = 0.2f * sp + 0.8f * hm[m][r];
                    hm[m][r] = hn;
                    hist[hb + (size_t)(m * 16 + q * 4 + r) * 1024
                            + s * 64 + wave * 16 + mrow] = (_Float16)hn;
                }
            }
        }
        // drain hist stores (vm) + LDS ops, then signal
        asm volatile("s_waitcnt vmcnt(0) lgkmcnt(0)\n\ts_barrier" ::: "memory"); // B2
        if (tid == 0) {
            if (fast) varr[g * 16 + s] = t + 2;   // write-through -> local L2
            else {
                __builtin_amdgcn_fence(__ATOMIC_RELEASE, "agent");
                __hip_atomic_store(&arr[g * 16 + s], t + 2, __ATOMIC_RELAXED,
                                   __HIP_MEMORY_SCOPE_AGENT);
            }
        }
    }
}

// ---------------------------------------------------------------------------
__global__ __launch_bounds__(256) void k_out(
    const _Float16* __restrict__ h16, const _Float16* __restrict__ Wof,
    const float* __restrict__ b_out, float* __restrict__ y)
{
    int blk  = blockIdx.x;
    int wave = threadIdx.x >> 6, lane = threadIdx.x & 63;
    int mrow = lane & 15, q = lane >> 4;
    int t  = blk >> 2;
    int b  = (blk & 3) * 64 + wave * 16 + mrow;
    size_t hb = (size_t)t * 524288 + (size_t)(b >> 5) * 65536
              + (size_t)(b & 31) * 1024;
    const half8* Wo8 = (const half8*)Wof;

    f32x4 acc[3];
    #pragma unroll
    for (int nt = 0; nt < 3; ++nt) acc[nt] = (f32x4){0.f, 0.f, 0.f, 0.f};

    #pragma unroll 4
    for (int kk = 0; kk < 32; ++kk) {
        half8 a = *(const half8*)(h16 + hb + kk * 32 + q * 8);
        #pragma unroll
        for (int nt = 0; nt < 3; ++nt) {
            half8 bb = Wo8[(nt * 32 + kk) * 64 + lane];
            acc[nt] = __builtin_amdgcn_mfma_f32_16x16x32_f16(a, bb, acc[nt],
                                                             0, 0, 0);
        }
    }
    #pragma unroll
    for (int nt = 0; nt < 3; ++nt) {
        int o = nt * 16 + mrow;
        if (o < NOUT) {
            float bo = b_out[o];
            #pragma unroll
            for (int r = 0; r < 4; ++r) {
                size_t R = (size_t)blk * 64 + wave * 16 + q * 4 + r;
                y[R * NOUT + o] = acc[nt][r] + bo;
            }
        }
    }
}

// ---------------------------------------------------------------------------
extern "C" void kernel_launch(void* const* d_in, const int* in_sizes, int n_in,
                              void* d_out, int out_size, void* d_ws, size_t ws_size,
                              hipStream_t stream) {
    const float* x      = (const float*)d_in[0];
    float*       noise  = (float*)d_in[1];   // also carries fp16 h history
    const float* W_sens = (const float*)d_in[2];
    const float* b_sens = (const float*)d_in[3];
    const float* W_rule = (const float*)d_in[4];
    const float* W_rec  = (const float*)d_in[5];
    const float* b_rec  = (const float*)d_in[6];
    const float* W_out  = (const float*)d_in[7];
    const float* b_out  = (const float*)d_in[8];
    float*       y      = (float*)d_out;

    _Float16* wsp   = (_Float16*)d_ws;
    _Float16* Wrecf = wsp;
    _Float16* Wcf   = Wrecf + 1048576;
    _Float16* Wof   = Wcf   + 131072;
    int*      arr   = (int*)(Wof + 49152);   // 128 flags
    int*      xcdArr= arr + 128;             // 128 xcd ids

    k_convert<<<dim3(600), dim3(256), 0, stream>>>(W_sens, W_rule, W_rec, W_out,
                                                   Wrecf, Wcf, Wof);
    k_init<<<dim3(1), dim3(256), 0, stream>>>(arr);
    k_rnn<<<dim3(128), dim3(384), 0, stream>>>(x, noise, b_sens, b_rec,
                                               Wrecf, Wcf, arr, xcdArr);
    k_out<<<dim3(1024), dim3(256), 0, stream>>>((const _Float16*)noise, Wof,
                                                b_out, y);
}